// Round 9
// baseline (249.051 us; speedup 1.0000x reference)
//
#include <hip/hip_runtime.h>

#define BB 32
#define TT 128
#define II 256
#define HH 256
#define OO 128
#define FWID 512  // H + I

// Exchange: u64 slot = (stamp<<32)|float_bits(h). Run-relative stamps:
// base = run_id*130; step s consumes stamp >= base+s from parity s&1,
// publishes base+s+1 into parity (s+1)&1. Slots live in a zero-init
// __device__ array (no memset dispatch); run_id claimed per launch via a
// persistent atomic counter (my>>8, 256 blocks/launch). Stale stamps from
// run k-1 are < run k's base -> never false-ready. s=0 gather SKIPPED
// (h(0)=0 known). Overwrite safety: publish(s+1) only after this block's
// gather(s). Aligned 8B atomics cannot tear. Protocol proven R13-R20.
//
// R21 (from R20: concurrent-sc0sc1 poll/publish NULL->slightly worse;
// reverted to R18 gather/publish. All relay micro-levers now proven null):
// TWO-FLOOR MODEL: weight streaming W+lam+gam = 48MB/step over 34.5TB/s
// aggregate L2 = 1.39us/step floor == measured 1.45-1.5 across R13/R18/R20.
// Compiler streams because it targets the 128-VGPR occupancy tier
// (VGPR_Count~104) instead of using launch_bounds' 256 budget; resident
// state (~200 f32) FITS. FIX: amdgpu_waves_per_eu(2,2) pins occupancy to
// exactly 2 waves/EU -> allocator free to keep W2/Lm2/G2 in registers.
// Per-step L2 weight traffic -> 0. Signature: VGPR_Count ~190-256.
// Predicted: L2 co-binding -> kernel 130-160us; relay-only -> flat ~185
// (clean relay-floor measurement, next move structural).

typedef unsigned long long u64;
typedef float f32x2 __attribute__((ext_vector_type(2)));

__device__ u64 g_slots[2ull * BB * HH];   // zero-initialized at module load
__device__ unsigned g_run_ctr = 0;        // persistent across graph replays

__device__ __forceinline__ f32x2 mk2(float a, float b) { f32x2 r; r.x = a; r.y = b; return r; }

__device__ __forceinline__ f32x2 pk_fma(f32x2 a, f32x2 b, f32x2 c) {
    f32x2 d;
    asm("v_pk_fma_f32 %0, %1, %2, %3" : "=v"(d) : "v"(a), "v"(b), "v"(c));
    return d;
}
__device__ __forceinline__ f32x2 pk_mul(f32x2 a, f32x2 b) {
    f32x2 d;
    asm("v_pk_mul_f32 %0, %1, %2" : "=v"(d) : "v"(a), "v"(b));
    return d;
}
__device__ __forceinline__ f32x2 pk_add(f32x2 a, f32x2 b) {
    f32x2 d;
    asm("v_pk_add_f32 %0, %1, %2" : "=v"(d) : "v"(a), "v"(b));
    return d;
}

template<int CTRL>
__device__ __forceinline__ float dpp_add(float x) {
    int t = __builtin_amdgcn_update_dpp(0, __float_as_int(x), CTRL, 0xF, 0xF, true);
    return x + __int_as_float(t);
}
// 16-lane butterfly sum via DPP row_ror; result valid in all 16 lanes.
__device__ __forceinline__ float row16_sum(float x) {
    x = dpp_add<0x128>(x);  // row_ror:8
    x = dpp_add<0x124>(x);  // row_ror:4
    x = dpp_add<0x122>(x);  // row_ror:2
    x = dpp_add<0x121>(x);  // row_ror:1
    return x;
}
// Paired version: interleaves the two dep chains (half the serial latency).
__device__ __forceinline__ void row16_sum2(float& a, float& b) {
    a = dpp_add<0x128>(a); b = dpp_add<0x128>(b);
    a = dpp_add<0x124>(a); b = dpp_add<0x124>(b);
    a = dpp_add<0x122>(a); b = dpp_add<0x122>(b);
    a = dpp_add<0x121>(a); b = dpp_add<0x121>(b);
}

__device__ __forceinline__ u64 slot_ld(const u64* p) {
    return __hip_atomic_load(p, __ATOMIC_RELAXED, __HIP_MEMORY_SCOPE_AGENT);
}

// One wave gathers 256 rows of one batch (4 slots/lane), stages h to LDS
// (ds_write_b128), release-stores an LDS flag. Depth-2 pipelined poll
// (R18-proven best variant).
__device__ __forceinline__ void gather_to_lds(const u64* base_p, int lane, unsigned us,
                                              float* dst, int* flag, int fval) {
    const u64* p = base_p + 4 * lane;
    u64 a, b, c, d;
    {
        u64 a0 = slot_ld(p), b0 = slot_ld(p + 1), c0 = slot_ld(p + 2), d0 = slot_ld(p + 3);
        for (;;) {
            u64 a1 = slot_ld(p), b1 = slot_ld(p + 1), c1 = slot_ld(p + 2), d1 = slot_ld(p + 3);
            bool ok0 = ((unsigned)(a0 >> 32) >= us) & ((unsigned)(b0 >> 32) >= us) &
                       ((unsigned)(c0 >> 32) >= us) & ((unsigned)(d0 >> 32) >= us);
            if (__all(ok0)) { a = a0; b = b0; c = c0; d = d0; break; }
            a0 = slot_ld(p); b0 = slot_ld(p + 1); c0 = slot_ld(p + 2); d0 = slot_ld(p + 3);
            bool ok1 = ((unsigned)(a1 >> 32) >= us) & ((unsigned)(b1 >> 32) >= us) &
                       ((unsigned)(c1 >> 32) >= us) & ((unsigned)(d1 >> 32) >= us);
            if (__all(ok1)) { a = a1; b = b1; c = c1; d = d1; break; }
        }
    }
    float4 hv;
    hv.x = __uint_as_float((unsigned)a);
    hv.y = __uint_as_float((unsigned)b);
    hv.z = __uint_as_float((unsigned)c);
    hv.w = __uint_as_float((unsigned)d);
    *reinterpret_cast<float4*>(dst + 4 * lane) = hv;
    if (lane == 0)  // release drains the wave's ds_write before the flag
        __hip_atomic_store(flag, fval, __ATOMIC_RELEASE, __HIP_MEMORY_SCOPE_WORKGROUP);
}

__global__ __launch_bounds__(512, 2) __attribute__((amdgpu_waves_per_eu(2, 2)))
void stpn_kernel(const float* __restrict__ x,      // (B,T,I)
                 const float* __restrict__ wlam,   // (H,FWID)
                 const float* __restrict__ wgam,   // (H,FWID)
                 const float* __restrict__ w,      // (H,FWID)
                 const float* __restrict__ bias,   // (H)
                 const float* __restrict__ wout,   // (O,H)
                 const float* __restrict__ bout,   // (O)
                 float* __restrict__ out)          // tag(4096) | h_T(8192) | F_T
{
    __shared__ __align__(16) float lh[2][HH];      // [parity][row]
    __shared__ int lflag[2];                       // [parity]
    __shared__ unsigned sbase;

    const int tid  = threadIdx.x;
    const int bk   = blockIdx.x;
    const int b    = bk & 31;        // batch
    const int sl   = bk >> 5;        // row slice 0..7 (32 rows each)
    const int wv   = tid >> 6;       // 0..7
    const int lane = tid & 63;
    const int g    = tid >> 4;       // 16-lane group 0..31 == row-within-slice
    const int i    = tid & 15;       // lane within group
    const int r    = sl * 32 + (g & 31);

    if (tid == 0) {
        unsigned my = __hip_atomic_fetch_add(&g_run_ctr, 1u,
                          __ATOMIC_RELAXED, __HIP_MEMORY_SCOPE_AGENT);
        sbase = (my >> 8) * 130u;    // 256 blocks per launch -> same run id
    }
    if (tid < 2) lflag[tid] = 0;

    // Per-lane f-chunks of row r: f = 64*k + 4*i + c, pair j = 2k+p covers c=2p,2p+1
    // (k<4 x-part, k>=4 h-part). With waves_per_eu(2,2) these stay REGISTER-
    // RESIDENT across the whole loop (the round's main lever).
    f32x2 W2[16], Lm2[16], G2[16], F2[16];
    {
        const float4* wr = reinterpret_cast<const float4*>(w    + (size_t)r * FWID);
        const float4* lr = reinterpret_cast<const float4*>(wlam + (size_t)r * FWID);
        const float4* gr = reinterpret_cast<const float4*>(wgam + (size_t)r * FWID);
#pragma unroll
        for (int k = 0; k < 8; ++k) {
            float4 t;
            t = wr[k * 16 + i]; W2[2*k]  = mk2(t.x, t.y); W2[2*k+1]  = mk2(t.z, t.w);
            t = lr[k * 16 + i]; Lm2[2*k] = mk2(t.x, t.y); Lm2[2*k+1] = mk2(t.z, t.w);
            t = gr[k * 16 + i]; G2[2*k]  = mk2(t.x, t.y); G2[2*k+1]  = mk2(t.z, t.w);
            F2[2*k] = mk2(0.f, 0.f); F2[2*k+1] = mk2(0.f, 0.f);
        }
    }
    const float bj = bias[r];
    float hl = 0.f;

    // preload x(0)
    float4 px0, px1, px2, px3;
    {
        const float4* xb4 = reinterpret_cast<const float4*>(x + (size_t)b * TT * II);
        px0 = xb4[i]; px1 = xb4[16 + i]; px2 = xb4[32 + i]; px3 = xb4[48 + i];
    }

    __syncthreads();   // sbase + lflag init visible
    const unsigned base = sbase;

    for (int s = 0; s < TT; ++s) {
        const int par = s & 1;

        f32x2 X2[8];
        X2[0] = mk2(px0.x, px0.y); X2[1] = mk2(px0.z, px0.w);
        X2[2] = mk2(px1.x, px1.y); X2[3] = mk2(px1.z, px1.w);
        X2[4] = mk2(px2.x, px2.y); X2[5] = mk2(px2.z, px2.w);
        X2[6] = mk2(px3.x, px3.y); X2[7] = mk2(px3.z, px3.w);

        // ---- Phase P: independent of h(s), runs before the gather ----
        f32x2 tw2[8];                                  // h-part tw, kept for dot_h
        f32x2 dx2 = mk2(0.f, 0.f), nv2 = mk2(0.f, 0.f);
#pragma unroll
        for (int j = 0; j < 8; ++j) {                  // x-part pairs
            f32x2 t = pk_add(W2[j], F2[j]);
            dx2 = pk_fma(X2[j], t, dx2);
            nv2 = pk_fma(t, t, nv2);
        }
#pragma unroll
        for (int j = 0; j < 8; ++j) {                  // h-part pairs
            tw2[j] = pk_add(W2[8 + j], F2[8 + j]);
            nv2 = pk_fma(tw2[j], tw2[j], nv2);
        }
        float dxs = dx2.x + dx2.y;
        float nrm = nv2.x + nv2.y;
        row16_sum2(dxs, nrm);
        const float invn = __builtin_amdgcn_rsqf(nrm);   // eps 1e-16 negligible, nrm = O(1)
        const f32x2 invn2 = mk2(invn, invn);
        const float dxb = dxs + bj;

        // F decay (h-independent)
#pragma unroll
        for (int j = 0; j < 16; ++j) F2[j] = pk_mul(Lm2[j], pk_mul(F2[j], invn2));

        // ---- gather h(s) (skip at s=0: h(0) == 0 by definition) ----
        float4 ha, hb, hc, hd;
        if (s != 0) {
            if (wv == 0) {
                __builtin_amdgcn_s_setprio(1);
                gather_to_lds(g_slots + ((size_t)par * BB + b) * HH, lane,
                              base + (unsigned)s, lh[par], &lflag[par], s + 1);
                __builtin_amdgcn_s_setprio(0);
            }
            while (__hip_atomic_load(&lflag[par], __ATOMIC_ACQUIRE, __HIP_MEMORY_SCOPE_WORKGROUP) <= s) {
                __builtin_amdgcn_s_sleep(1);
            }
            const float4* lh4 = reinterpret_cast<const float4*>(lh[par]);
            ha = lh4[i]; hb = lh4[16 + i]; hc = lh4[32 + i]; hd = lh4[48 + i];
        } else {
            ha = make_float4(0.f, 0.f, 0.f, 0.f); hb = ha; hc = ha; hd = ha;
        }
        f32x2 H2[8];
        H2[0] = mk2(ha.x, ha.y); H2[1] = mk2(ha.z, ha.w);
        H2[2] = mk2(hb.x, hb.y); H2[3] = mk2(hb.z, hb.w);
        H2[4] = mk2(hc.x, hc.y); H2[5] = mk2(hc.z, hc.w);
        H2[6] = mk2(hd.x, hd.y); H2[7] = mk2(hd.z, hd.w);

        // dot_h: 2 packed chains of 4 + combine (short dep depth)
        f32x2 a2 = pk_mul(H2[0], tw2[0]);
        f32x2 b2 = pk_mul(H2[1], tw2[1]);
        a2 = pk_fma(H2[2], tw2[2], a2);
        b2 = pk_fma(H2[3], tw2[3], b2);
        a2 = pk_fma(H2[4], tw2[4], a2);
        b2 = pk_fma(H2[5], tw2[5], b2);
        a2 = pk_fma(H2[6], tw2[6], a2);
        b2 = pk_fma(H2[7], tw2[7], b2);
        f32x2 c2 = pk_add(a2, b2);
        float dh = c2.x + c2.y;
        dh = row16_sum(dh);

        const float e = __expf(2.0f * (dxb + dh));
        const float h = (1.0f - 2.0f * __builtin_amdgcn_rcpf(e + 1.0f)) * invn;
        hl = h;

        // publish ASAP (relaxed agent store, no fence — R18-proven path)
        if (i == 0) {
            const u64 val = ((u64)(base + (unsigned)s + 1u) << 32) | (unsigned)__float_as_uint(h);
            __hip_atomic_store(g_slots + ((size_t)(par ^ 1) * BB + b) * HH + r, val,
                               __ATOMIC_RELAXED, __HIP_MEMORY_SCOPE_AGENT);
        }

        // x(s+1) prefetch: in flight under Phase U, consumed at next loop top
        if (s + 1 < TT) {
            const float4* xn = reinterpret_cast<const float4*>(x + ((size_t)b * TT + (s + 1)) * II);
            px0 = xn[i]; px1 = xn[16 + i]; px2 = xn[32 + i]; px3 = xn[48 + i];
        }

        // ---- Phase U: F += (gamma*input)*h ----
        const f32x2 h2v = mk2(h, h);
#pragma unroll
        for (int j = 0; j < 8; ++j)
            F2[j] = pk_fma(pk_mul(X2[j], G2[j]), h2v, F2[j]);
#pragma unroll
        for (int j = 0; j < 8; ++j)
            F2[8 + j] = pk_fma(pk_mul(G2[8 + j], H2[j]), h2v, F2[8 + j]);
    }

    // ---- epilogue: F_T, h_T ----
    {
        float4* fo = reinterpret_cast<float4*>(out + 12288 + ((size_t)b * HH + r) * FWID);
#pragma unroll
        for (int k = 0; k < 8; ++k) {
            float4 v;
            v.x = F2[2*k].x; v.y = F2[2*k].y; v.z = F2[2*k+1].x; v.w = F2[2*k+1].y;
            fo[k * 16 + i] = v;
        }
    }
    if (i == 0) out[4096 + (size_t)b * HH + r] = hl;

    // tag_space: sl==0 blocks (one per batch) gather final h (stamp base+TT)
    if (sl == 0) {
        if (wv == 0) {
            gather_to_lds(g_slots + ((size_t)(TT & 1) * BB + b) * HH, lane,
                          base + (unsigned)TT, lh[0], &lflag[0], TT + 1);
        }
        while (__hip_atomic_load(&lflag[0], __ATOMIC_ACQUIRE, __HIP_MEMORY_SCOPE_WORKGROUP) <= TT) {
            __builtin_amdgcn_s_sleep(1);
        }
        if (tid < OO) {
            const float* hv = lh[0];
            float acc = bout[tid];
            const float* wo = wout + (size_t)tid * HH;
#pragma unroll 4
            for (int jj = 0; jj < HH; ++jj) acc = fmaf(wo[jj], hv[jj], acc);
            out[(size_t)b * OO + tid] = acc;
        }
    }
}

extern "C" void kernel_launch(void* const* d_in, const int* in_sizes, int n_in,
                              void* d_out, int out_size, void* d_ws, size_t ws_size,
                              hipStream_t stream) {
    (void)in_sizes; (void)n_in; (void)out_size; (void)d_ws; (void)ws_size;
    const float* x    = (const float*)d_in[0];
    const float* wlam = (const float*)d_in[1];
    const float* wgam = (const float*)d_in[2];
    const float* w    = (const float*)d_in[3];
    const float* bias = (const float*)d_in[4];
    const float* wout = (const float*)d_in[5];
    const float* bout = (const float*)d_in[6];
    float* out = (float*)d_out;

    // No memset node: slots live in zero-init __device__ memory with
    // run-relative stamps (see header comment). Single graph node.
    // Plain launch: grid 256 <= co-residency capacity (launch_bounds(512,2));
    // no grid-wide sync primitive is used (R14: coop replay cost ~40-75us).
    hipLaunchKernelGGL(stpn_kernel, dim3(256), dim3(512), 0, stream,
                       x, wlam, wgam, w, bias, wout, bout, out);
}

// Round 10
// 220.700 us; speedup vs baseline: 1.1285x; 1.1285x over previous
//
#include <hip/hip_runtime.h>

#define BB 32
#define TT 128
#define II 256
#define HH 256
#define OO 128
#define FWID 512  // H + I

// d_ws: u64 slots[2][BB][HH] (parity, batch, row) = 128 KB.
// Slot = (stamp<<32)|float_bits(h); step s consumes stamp>=s from parity s&1,
// publishes stamp s+1 into parity (s+1)&1. Agent-scope relaxed (no fences);
// protocol proven on HW. Overwrite safety: publish(s+1) only after this
// block's gather(s) => all stamp-(s-1) readers retired. u64 cannot tear.
//
// R22 = R18 (best kernel 183-186us; d_ws slots + memset restored — R20/R21's
// __device__-global slots measured ~8us slower) + FORCED REGISTER RESIDENCY:
//  - R21 showed waves_per_eu(2,2) applies (SGPR 48->32) but does NOT stop the
//    scheduler from sinking W/lam/gam loads into the loop (VGPR stuck at 108,
//    ~24 reload-b128/thread/step = 4.2 TB/s/XCD == per-XCD L2 ceiling ==
//    measured 1.45us/step; kernel runs AT the L2 BW floor).
//  - Fix: opacity barrier. After preload, pass every W2/Lm2/G2 register
//    through asm volatile("" : "+v"(reg)). Value becomes unknown -> remat
//    impossible -> must stay in VGPRs. Budget 256 (launch_bounds(512,2) +
//    waves_per_eu(2,2)); pinned 96 + live ~130 < 256; occupancy unchanged
//    (already 2 waves/SIMD).
// Signature: VGPR_Count 108 -> 200-256, no scratch (FETCH/WRITE flat).
// Predicted: L2-floor true -> kernel 110-140us, VALUBusy 55-70%;
// false (flat ~185 w/ high VGPR) -> relay floor confirmed, near-ceiling.

typedef unsigned long long u64;
typedef float f32x2 __attribute__((ext_vector_type(2)));

__device__ __forceinline__ f32x2 mk2(float a, float b) { f32x2 r; r.x = a; r.y = b; return r; }

__device__ __forceinline__ f32x2 pk_fma(f32x2 a, f32x2 b, f32x2 c) {
    f32x2 d;
    asm("v_pk_fma_f32 %0, %1, %2, %3" : "=v"(d) : "v"(a), "v"(b), "v"(c));
    return d;
}
__device__ __forceinline__ f32x2 pk_mul(f32x2 a, f32x2 b) {
    f32x2 d;
    asm("v_pk_mul_f32 %0, %1, %2" : "=v"(d) : "v"(a), "v"(b));
    return d;
}
__device__ __forceinline__ f32x2 pk_add(f32x2 a, f32x2 b) {
    f32x2 d;
    asm("v_pk_add_f32 %0, %1, %2" : "=v"(d) : "v"(a), "v"(b));
    return d;
}

template<int CTRL>
__device__ __forceinline__ float dpp_add(float x) {
    int t = __builtin_amdgcn_update_dpp(0, __float_as_int(x), CTRL, 0xF, 0xF, true);
    return x + __int_as_float(t);
}
// 16-lane butterfly sum via DPP row_ror; result valid in all 16 lanes.
__device__ __forceinline__ float row16_sum(float x) {
    x = dpp_add<0x128>(x);  // row_ror:8
    x = dpp_add<0x124>(x);  // row_ror:4
    x = dpp_add<0x122>(x);  // row_ror:2
    x = dpp_add<0x121>(x);  // row_ror:1
    return x;
}
// Paired version: interleaves the two dep chains (half the serial latency).
__device__ __forceinline__ void row16_sum2(float& a, float& b) {
    a = dpp_add<0x128>(a); b = dpp_add<0x128>(b);
    a = dpp_add<0x124>(a); b = dpp_add<0x124>(b);
    a = dpp_add<0x122>(a); b = dpp_add<0x122>(b);
    a = dpp_add<0x121>(a); b = dpp_add<0x121>(b);
}

__device__ __forceinline__ u64 slot_ld(const u64* p) {
    return __hip_atomic_load(p, __ATOMIC_RELAXED, __HIP_MEMORY_SCOPE_AGENT);
}

// One wave gathers 256 rows of one batch (4 slots/lane), stages h to LDS
// (ds_write_b128), release-stores an LDS flag. Depth-2 pipelined poll
// (R18-proven variant).
__device__ __forceinline__ void gather_to_lds(const u64* base, int lane, unsigned us,
                                              float* dst, int* flag, int fval) {
    const u64* p = base + 4 * lane;
    u64 a, b, c, d;
    {
        u64 a0 = slot_ld(p), b0 = slot_ld(p + 1), c0 = slot_ld(p + 2), d0 = slot_ld(p + 3);
        for (;;) {
            u64 a1 = slot_ld(p), b1 = slot_ld(p + 1), c1 = slot_ld(p + 2), d1 = slot_ld(p + 3);
            bool ok0 = ((unsigned)(a0 >> 32) >= us) & ((unsigned)(b0 >> 32) >= us) &
                       ((unsigned)(c0 >> 32) >= us) & ((unsigned)(d0 >> 32) >= us);
            if (__all(ok0)) { a = a0; b = b0; c = c0; d = d0; break; }
            a0 = slot_ld(p); b0 = slot_ld(p + 1); c0 = slot_ld(p + 2); d0 = slot_ld(p + 3);
            bool ok1 = ((unsigned)(a1 >> 32) >= us) & ((unsigned)(b1 >> 32) >= us) &
                       ((unsigned)(c1 >> 32) >= us) & ((unsigned)(d1 >> 32) >= us);
            if (__all(ok1)) { a = a1; b = b1; c = c1; d = d1; break; }
        }
    }
    float4 hv;
    hv.x = __uint_as_float((unsigned)a);
    hv.y = __uint_as_float((unsigned)b);
    hv.z = __uint_as_float((unsigned)c);
    hv.w = __uint_as_float((unsigned)d);
    *reinterpret_cast<float4*>(dst + 4 * lane) = hv;
    if (lane == 0)  // release drains the wave's ds_write before the flag
        __hip_atomic_store(flag, fval, __ATOMIC_RELEASE, __HIP_MEMORY_SCOPE_WORKGROUP);
}

__global__ __launch_bounds__(512, 2) __attribute__((amdgpu_waves_per_eu(2, 2)))
void stpn_kernel(const float* __restrict__ x,      // (B,T,I)
                 const float* __restrict__ wlam,   // (H,FWID)
                 const float* __restrict__ wgam,   // (H,FWID)
                 const float* __restrict__ w,      // (H,FWID)
                 const float* __restrict__ bias,   // (H)
                 const float* __restrict__ wout,   // (O,H)
                 const float* __restrict__ bout,   // (O)
                 float* __restrict__ out,          // tag(4096) | h_T(8192) | F_T
                 u64* __restrict__ slots)
{
    __shared__ __align__(16) float lh[2][HH];      // [parity][row]
    __shared__ int lflag[2];                       // [parity]

    const int tid  = threadIdx.x;
    const int bk   = blockIdx.x;
    const int b    = bk & 31;        // batch
    const int sl   = bk >> 5;        // row slice 0..7 (32 rows each)
    const int wv   = tid >> 6;       // 0..7
    const int lane = tid & 63;
    const int g    = tid >> 4;       // 16-lane group 0..31 == row-within-slice
    const int i    = tid & 15;       // lane within group
    const int r    = sl * 32 + (g & 31);

    if (tid < 2) lflag[tid] = 0;

    // Per-lane f-chunks of row r: f = 64*k + 4*i + c, pair j = 2k+p covers c=2p,2p+1
    // (k<4 x-part, k>=4 h-part)
    f32x2 W2[16], Lm2[16], G2[16], F2[16];
    {
        const float4* wr = reinterpret_cast<const float4*>(w    + (size_t)r * FWID);
        const float4* lr = reinterpret_cast<const float4*>(wlam + (size_t)r * FWID);
        const float4* gr = reinterpret_cast<const float4*>(wgam + (size_t)r * FWID);
#pragma unroll
        for (int k = 0; k < 8; ++k) {
            float4 t;
            t = wr[k * 16 + i]; W2[2*k]  = mk2(t.x, t.y); W2[2*k+1]  = mk2(t.z, t.w);
            t = lr[k * 16 + i]; Lm2[2*k] = mk2(t.x, t.y); Lm2[2*k+1] = mk2(t.z, t.w);
            t = gr[k * 16 + i]; G2[2*k]  = mk2(t.x, t.y); G2[2*k+1]  = mk2(t.z, t.w);
            F2[2*k] = mk2(0.f, 0.f); F2[2*k+1] = mk2(0.f, 0.f);
        }
    }
    // OPACITY BARRIER: values become unknown to the compiler -> it cannot
    // rematerialize the loads inside the loop; W/lam/gam stay in VGPRs.
#pragma unroll
    for (int j = 0; j < 16; ++j) {
        asm volatile("" : "+v"(W2[j]));
        asm volatile("" : "+v"(Lm2[j]));
        asm volatile("" : "+v"(G2[j]));
    }
    const float bj = bias[r];
    float hl = 0.f;

    // preload x(0)
    float4 px0, px1, px2, px3;
    {
        const float4* xb4 = reinterpret_cast<const float4*>(x + (size_t)b * TT * II);
        px0 = xb4[i]; px1 = xb4[16 + i]; px2 = xb4[32 + i]; px3 = xb4[48 + i];
    }

    __syncthreads();   // lflag init visible

    for (int s = 0; s < TT; ++s) {
        const int par = s & 1;

        f32x2 X2[8];
        X2[0] = mk2(px0.x, px0.y); X2[1] = mk2(px0.z, px0.w);
        X2[2] = mk2(px1.x, px1.y); X2[3] = mk2(px1.z, px1.w);
        X2[4] = mk2(px2.x, px2.y); X2[5] = mk2(px2.z, px2.w);
        X2[6] = mk2(px3.x, px3.y); X2[7] = mk2(px3.z, px3.w);

        // ---- Phase P: independent of h(s), runs before the gather ----
        f32x2 tw2[8];                                  // h-part tw, kept for dot_h
        f32x2 dx2 = mk2(0.f, 0.f), nv2 = mk2(0.f, 0.f);
#pragma unroll
        for (int j = 0; j < 8; ++j) {                  // x-part pairs
            f32x2 t = pk_add(W2[j], F2[j]);
            dx2 = pk_fma(X2[j], t, dx2);
            nv2 = pk_fma(t, t, nv2);
        }
#pragma unroll
        for (int j = 0; j < 8; ++j) {                  // h-part pairs
            tw2[j] = pk_add(W2[8 + j], F2[8 + j]);
            nv2 = pk_fma(tw2[j], tw2[j], nv2);
        }
        float dxs = dx2.x + dx2.y;
        float nrm = nv2.x + nv2.y;
        row16_sum2(dxs, nrm);
        const float invn = __builtin_amdgcn_rsqf(nrm);   // eps 1e-16 negligible, nrm = O(1)
        const f32x2 invn2 = mk2(invn, invn);
        const float dxb = dxs + bj;

        // F decay (h-independent)
#pragma unroll
        for (int j = 0; j < 16; ++j) F2[j] = pk_mul(Lm2[j], pk_mul(F2[j], invn2));

        // ---- gather (wave 0, pipelined after Phase P; prio-boosted) ----
        if (wv == 0) {
            __builtin_amdgcn_s_setprio(1);
            gather_to_lds(slots + ((size_t)par * BB + b) * HH, lane,
                          (unsigned)s, lh[par], &lflag[par], s + 1);
            __builtin_amdgcn_s_setprio(0);
        }

        // ---- Phase W: LDS flag spin (sleep frees SIMD issue), consume h ----
        while (__hip_atomic_load(&lflag[par], __ATOMIC_ACQUIRE, __HIP_MEMORY_SCOPE_WORKGROUP) <= s) {
            __builtin_amdgcn_s_sleep(1);
        }
        const float4* lh4 = reinterpret_cast<const float4*>(lh[par]);
        float4 ha = lh4[i], hb = lh4[16 + i], hc = lh4[32 + i], hd = lh4[48 + i];
        f32x2 H2[8];
        H2[0] = mk2(ha.x, ha.y); H2[1] = mk2(ha.z, ha.w);
        H2[2] = mk2(hb.x, hb.y); H2[3] = mk2(hb.z, hb.w);
        H2[4] = mk2(hc.x, hc.y); H2[5] = mk2(hc.z, hc.w);
        H2[6] = mk2(hd.x, hd.y); H2[7] = mk2(hd.z, hd.w);

        // dot_h: 2 packed chains of 4 + combine (short dep depth)
        f32x2 a2 = pk_mul(H2[0], tw2[0]);
        f32x2 b2 = pk_mul(H2[1], tw2[1]);
        a2 = pk_fma(H2[2], tw2[2], a2);
        b2 = pk_fma(H2[3], tw2[3], b2);
        a2 = pk_fma(H2[4], tw2[4], a2);
        b2 = pk_fma(H2[5], tw2[5], b2);
        a2 = pk_fma(H2[6], tw2[6], a2);
        b2 = pk_fma(H2[7], tw2[7], b2);
        f32x2 c2 = pk_add(a2, b2);
        float dh = c2.x + c2.y;
        dh = row16_sum(dh);

        const float e = __expf(2.0f * (dxb + dh));
        const float h = (1.0f - 2.0f * __builtin_amdgcn_rcpf(e + 1.0f)) * invn;
        hl = h;

        // publish ASAP (relaxed agent store, no fence)
        if (i == 0) {
            __hip_atomic_store(slots + ((size_t)(par ^ 1) * BB + b) * HH + r,
                               ((u64)(unsigned)(s + 1) << 32) | (unsigned)__float_as_uint(h),
                               __ATOMIC_RELAXED, __HIP_MEMORY_SCOPE_AGENT);
        }

        // x(s+1) prefetch: in flight under Phase U, consumed at next loop top
        if (s + 1 < TT) {
            const float4* xn = reinterpret_cast<const float4*>(x + ((size_t)b * TT + (s + 1)) * II);
            px0 = xn[i]; px1 = xn[16 + i]; px2 = xn[32 + i]; px3 = xn[48 + i];
        }

        // ---- Phase U: F += (gamma*input)*h ----
        const f32x2 h2v = mk2(h, h);
#pragma unroll
        for (int j = 0; j < 8; ++j)
            F2[j] = pk_fma(pk_mul(X2[j], G2[j]), h2v, F2[j]);
#pragma unroll
        for (int j = 0; j < 8; ++j)
            F2[8 + j] = pk_fma(pk_mul(G2[8 + j], H2[j]), h2v, F2[8 + j]);
    }

    // ---- epilogue: F_T, h_T ----
    {
        float4* fo = reinterpret_cast<float4*>(out + 12288 + ((size_t)b * HH + r) * FWID);
#pragma unroll
        for (int k = 0; k < 8; ++k) {
            float4 v;
            v.x = F2[2*k].x; v.y = F2[2*k].y; v.z = F2[2*k+1].x; v.w = F2[2*k+1].y;
            fo[k * 16 + i] = v;
        }
    }
    if (i == 0) out[4096 + (size_t)b * HH + r] = hl;

    // tag_space: sl==0 blocks (one per batch) gather final h (stamp TT, parity 0)
    if (sl == 0) {
        if (wv == 0) {
            gather_to_lds(slots + ((size_t)(TT & 1) * BB + b) * HH, lane,
                          (unsigned)TT, lh[0], &lflag[0], TT + 1);
        }
        while (__hip_atomic_load(&lflag[0], __ATOMIC_ACQUIRE, __HIP_MEMORY_SCOPE_WORKGROUP) <= TT) {
            __builtin_amdgcn_s_sleep(1);
        }
        if (tid < OO) {
            const float* hv = lh[0];
            float acc = bout[tid];
            const float* wo = wout + (size_t)tid * HH;
#pragma unroll 4
            for (int jj = 0; jj < HH; ++jj) acc = fmaf(wo[jj], hv[jj], acc);
            out[(size_t)b * OO + tid] = acc;
        }
    }
}

extern "C" void kernel_launch(void* const* d_in, const int* in_sizes, int n_in,
                              void* d_out, int out_size, void* d_ws, size_t ws_size,
                              hipStream_t stream) {
    (void)in_sizes; (void)n_in; (void)out_size; (void)ws_size;
    const float* x    = (const float*)d_in[0];
    const float* wlam = (const float*)d_in[1];
    const float* wgam = (const float*)d_in[2];
    const float* w    = (const float*)d_in[3];
    const float* bias = (const float*)d_in[4];
    const float* wout = (const float*)d_in[5];
    const float* bout = (const float*)d_in[6];
    float* out = (float*)d_out;

    u64* slots = (u64*)d_ws;

    // stamp 0 + h = 0.0 is exactly what step 0 consumes
    hipMemsetAsync(d_ws, 0, 2ull * BB * HH * 8ull, stream);

    // Plain launch: grid 256 <= co-residency capacity (launch_bounds(512,2));
    // no grid-wide sync primitive is used (R14: coop replay cost ~40-75us).
    hipLaunchKernelGGL(stpn_kernel, dim3(256), dim3(512), 0, stream,
                       x, wlam, wgam, w, bias, wout, bout, out, slots);
}